// Round 14
// baseline (114.873 us; speedup 1.0000x reference)
//
#include <hip/hip_runtime.h>
#include <math.h>

#define N_ATOMS 20000
#define G_GRAPHS 500
#define NPG 40
#define DEG 16
#define E_EDGES (N_ATOMS * DEG)
#define EPM (NPG * DEG)          // 640 real edges per molecule
#define EPAD 680                 // padded capacity (each atom even count)
#define HID 128
#define NF 128
#define TBL2 80
#define TROWS (TBL2 + 2)         // 82 stored rows (grid -1 .. 80)
#define PROWS 81                 // pair rows s=0..80: (row s, row s+1)
#define CUTOFF 10.0f
#define LOG2F_ 0.6931471805599453f

typedef __attribute__((ext_vector_type(8))) short short8v;
typedef __attribute__((ext_vector_type(4))) float f32x4;
typedef __attribute__((ext_vector_type(2))) __bf16 bf16x2;
typedef unsigned short ushort_t;

__device__ __forceinline__ float ssp_f(float x) {
  float ax = fabsf(x);
  return fmaxf(x, 0.0f) + log1pf(expf(-ax)) - LOG2F_;
}
// native RNE float->bf16 (compiler emits v_cvt_*_bf16; RNE == manual round-nearest-even)
__device__ __forceinline__ ushort_t bf16rne(float x) {
  __bf16 b = (__bf16)x;
  return __builtin_bit_cast(ushort_t, b);
}
__device__ __forceinline__ unsigned pk2(float a, float b) {
  return (unsigned)bf16rne(a) | ((unsigned)bf16rne(b) << 16);
}
__device__ __forceinline__ float bflo(unsigned u) { return __uint_as_float(u << 16); }
__device__ __forceinline__ float bfhi(unsigned u) { return __uint_as_float(u & 0xFFFF0000u); }
__device__ __forceinline__ int bidx(int row, int col) {
  return row * 128 + (col ^ ((row & 7) << 3));
}
__device__ __forceinline__ float fdot2b(unsigned a, unsigned b, float c) {
#if defined(__has_builtin) && __has_builtin(__builtin_amdgcn_fdot2_f32_bf16)
  return __builtin_amdgcn_fdot2_f32_bf16(__builtin_bit_cast(bf16x2, a),
                                         __builtin_bit_cast(bf16x2, b), c, false);
#else
  return fmaf(bflo(a), bflo(b), fmaf(bfhi(a), bfhi(b), c));
#endif
}

// ================= merged preamble: table(33) | prep(38) | csr(500) =================
__global__ void __launch_bounds__(512) k_pre(
    const float* __restrict__ mlp_w1, const float* __restrict__ mlp_b1,
    const float* __restrict__ mlp_w2, const float* __restrict__ mlp_b2,
    const float* __restrict__ cf_w1, const float* __restrict__ cf_w2,
    const float* __restrict__ lin_w, const float* __restrict__ hw1,
    const float* __restrict__ pos, const int* __restrict__ ei,
    unsigned* __restrict__ ptabg, ushort_t* __restrict__ wtb,
    uint4* __restrict__ ge, int* __restrict__ gstart) {
  int b = blockIdx.x;
  int t = threadIdx.x;

  if (b < 33) {
    // ---------- filter-table role: 8 rows per block, pair-packed global output ----------
    __shared__ float eaT[NF][8];
    __shared__ float hvT[NF][8];
    int l = b / 11;
    int rbase = (b % 11) * 8;
    const float* w1 = mlp_w1 + (size_t)l * NF * NF;
    const float* b1 = mlp_b1 + (size_t)l * NF;
    const float* w2 = mlp_w2 + (size_t)l * NF * NF;
    const float* b2 = mlp_b2 + (size_t)l * NF;
    ushort_t* pp = (ushort_t*)(ptabg + (size_t)l * PROWS * 128);
    const float hh = CUTOFF / (float)(TBL2 - 1);
    const float delta = CUTOFF / (float)(NF - 1);
    const float coeff = -0.5f / (delta * delta);
    int j = t & 127;
    bool act = t < 128;
    if (act) {
#pragma unroll
      for (int rr = 0; rr < 8; ++rr) {
        float d = ((float)(rbase + rr) - 1.0f) * hh;
        float tt = d - delta * (float)j;
        eaT[j][rr] = expf(coeff * tt * tt);
      }
    }
    __syncthreads();
    float acc[8], wreg[16];
    if (act) {
      float b1j = b1[j];
#pragma unroll
      for (int rr = 0; rr < 8; ++rr) acc[rr] = b1j;
      for (int kb = 0; kb < NF; kb += 16) {
#pragma unroll
        for (int i = 0; i < 16; ++i) wreg[i] = w1[(kb + i) * NF + j];
#pragma unroll
        for (int i = 0; i < 16; ++i) {
          float4 e0 = *(const float4*)&eaT[kb + i][0];
          float4 e1 = *(const float4*)&eaT[kb + i][4];
          float wv = wreg[i];
          acc[0] = fmaf(e0.x, wv, acc[0]); acc[1] = fmaf(e0.y, wv, acc[1]);
          acc[2] = fmaf(e0.z, wv, acc[2]); acc[3] = fmaf(e0.w, wv, acc[3]);
          acc[4] = fmaf(e1.x, wv, acc[4]); acc[5] = fmaf(e1.y, wv, acc[5]);
          acc[6] = fmaf(e1.z, wv, acc[6]); acc[7] = fmaf(e1.w, wv, acc[7]);
        }
      }
#pragma unroll
      for (int rr = 0; rr < 8; ++rr) hvT[j][rr] = ssp_f(acc[rr]);
    }
    __syncthreads();
    if (act) {
      float b2j = b2[j];
#pragma unroll
      for (int rr = 0; rr < 8; ++rr) acc[rr] = b2j;
      for (int kb = 0; kb < NF; kb += 16) {
#pragma unroll
        for (int i = 0; i < 16; ++i) wreg[i] = w2[(kb + i) * NF + j];
#pragma unroll
        for (int i = 0; i < 16; ++i) {
          float4 e0 = *(const float4*)&hvT[kb + i][0];
          float4 e1 = *(const float4*)&hvT[kb + i][4];
          float wv = wreg[i];
          acc[0] = fmaf(e0.x, wv, acc[0]); acc[1] = fmaf(e0.y, wv, acc[1]);
          acc[2] = fmaf(e0.z, wv, acc[2]); acc[3] = fmaf(e0.w, wv, acc[3]);
          acc[4] = fmaf(e1.x, wv, acc[4]); acc[5] = fmaf(e1.y, wv, acc[5]);
          acc[6] = fmaf(e1.z, wv, acc[6]); acc[7] = fmaf(e1.w, wv, acc[7]);
        }
      }
#pragma unroll
      for (int rr = 0; rr < 8; ++rr) {
        int s = rbase + rr;
        if (s < TROWS) {
          float d = ((float)s - 1.0f) * hh;
          float C = 0.5f * (cosf(d * (float)M_PI / CUTOFF) + 1.0f);
          ushort_t v = bf16rne(acc[rr] * C);
          if (s < PROWS) pp[(s * 128 + j) * 2] = v;          // low half of pair s
          if (s >= 1) pp[((s - 1) * 128 + j) * 2 + 1] = v;   // high half of pair s-1
        }
      }
    }
  } else if (b < 71) {
    // ---------- weight transpose role ----------
    __shared__ float tile[32][33];
    int pb = b - 33;
    int tr = (t & 255) >> 5, tc = t & 31;
    bool act = t < 256;
    if (pb < 36) {
      int m = pb >> 2, tj = pb & 3;
      int l = m / 3, ty = m % 3;
      const float* src = (ty == 0 ? cf_w1 : ty == 1 ? cf_w2 : lin_w) + (size_t)l * 128 * 128;
      ushort_t* dst = wtb + (size_t)m * 128 * 128;
      for (int ti = 0; ti < 4; ++ti) {
        __syncthreads();
        if (act) {
#pragma unroll
          for (int i = 0; i < 4; ++i) {
            int r = tr + i * 8;
            tile[r][tc] = src[(ti * 32 + r) * 128 + tj * 32 + tc];
          }
        }
        __syncthreads();
        if (act) {
#pragma unroll
          for (int i = 0; i < 4; ++i) {
            int r = tr + i * 8;
            dst[(tj * 32 + r) * 128 + ti * 32 + tc] = bf16rne(tile[tc][r]);
          }
        }
      }
    } else {
      int tj = pb - 36;
      ushort_t* dst = wtb + (size_t)9 * 128 * 128;
      for (int ti = 0; ti < 4; ++ti) {
        __syncthreads();
        if (act) {
#pragma unroll
          for (int i = 0; i < 4; ++i) {
            int r = tr + i * 8;
            tile[r][tc] = hw1[(ti * 32 + r) * 64 + tj * 32 + tc];
          }
        }
        __syncthreads();
        if (act) {
#pragma unroll
          for (int i = 0; i < 4; ++i) {
            int r = tr + i * 8;
            dst[(tj * 32 + r) * 128 + ti * 32 + tc] = bf16rne(tile[tc][r]);
          }
        }
      }
    }
  } else {
    // ---------- CSR role: distances + cubic weights + even-padded CSR ----------
    __shared__ float spos[NPG * 3];
    __shared__ int cnt[NPG];
    __shared__ int pfx[NPG + 1];
    __shared__ uint4 epk[EPM];
    __shared__ unsigned char ecol[EPM];
    __shared__ short ssidx[EPAD];
    int g = b - 71, a0 = g * NPG;
    if (t < NPG * 3) spos[t] = pos[a0 * 3 + t];
    if (t < NPG) cnt[t] = 0;
    for (int i = t; i < EPAD; i += 512) ssidx[i] = -1;
    __syncthreads();
    int ebase = a0 * DEG;
    const float tscale = (float)(TBL2 - 1) / CUTOFF;
    for (int i = t; i < EPM; i += 512) {
      int r = ei[ebase + i] - a0;
      int c = ei[E_EDGES + ebase + i] - a0;
      float dx = spos[3 * r + 0] - spos[3 * c + 0];
      float dy = spos[3 * r + 1] - spos[3 * c + 1];
      float dz = spos[3 * r + 2] - spos[3 * c + 2];
      float ft = sqrtf(dx * dx + dy * dy + dz * dz) * tscale;
      int i0 = min((int)ft, TBL2 - 2);
      float tt = ft - (float)i0;
      float t2 = tt * tt, t3 = t2 * tt;
      float w0 = 0.5f * (-t3 + 2.f * t2 - tt);
      float w1 = 0.5f * (3.f * t3 - 5.f * t2 + 2.f);
      float w2 = 0.5f * (-3.f * t3 + 4.f * t2 + tt);
      float w3 = 0.5f * (t3 - t2);
      epk[i] = make_uint4(pk2(w0, w1), pk2(w2, w3), (unsigned)(i0 << 7),
                          (unsigned)((r << 6) | (((r & 7) << 2) << 16)));
      ecol[i] = (unsigned char)c;
      atomicAdd(&cnt[c], 1);
    }
    __syncthreads();
    if (t == 0) {
      int s = 0;
      for (int a = 0; a < NPG; ++a) { pfx[a] = s; s += (cnt[a] + 1) & ~1; }
      pfx[NPG] = s;
    }
    __syncthreads();
    int w = t >> 6, lane = t & 63;
    for (int a = w * 5; a < w * 5 + 5; ++a) {
      int p = pfx[a];
#pragma unroll
      for (int ch = 0; ch < EPM / 64; ++ch) {
        int e = ch * 64 + lane;
        bool match = ((int)ecol[e] == a);
        unsigned long long bal = __ballot(match);
        if (match) ssidx[p + __popcll(bal & ((1ull << lane) - 1ull))] = (short)e;
        p += __popcll(bal);
      }
    }
    __syncthreads();
    int ptot = pfx[NPG];
    const uint4 z4 = make_uint4(0u, 0u, 0u, 0u);
    for (int i = t; i < ptot; i += 512) {
      int e = ssidx[i];
      ge[(size_t)g * EPAD + i] = (e >= 0) ? epk[e] : z4;
    }
    if (t <= NPG) gstart[g * (NPG + 1) + t] = pfx[t];
  }
}

// ================= whole model per molecule =================
__global__ void __launch_bounds__(512) k_mol(
    const float* __restrict__ emb, const int* __restrict__ z,
    const uint4* __restrict__ ge, const int* __restrict__ gstart,
    const unsigned* __restrict__ ptabg, const ushort_t* __restrict__ wtb,
    const float* __restrict__ cf_b2, const float* __restrict__ lin_b,
    const float* __restrict__ hb1, const float* __restrict__ hw2,
    const float* __restrict__ hb2, float* __restrict__ out) {
  __shared__ unsigned ptab[PROWS * 128];  // 41,472 B pair-packed table
  __shared__ ushort_t sb0[48 * 128];      // 12,288 B
  __shared__ ushort_t sb1[48 * 128];      // 12,288 B
  __shared__ int sstart[NPG + 1];
  __shared__ float shead[48];
  __shared__ int sz[NPG];
  int g = blockIdx.x, a0 = g * NPG, t = threadIdx.x;
  int w = t >> 6, l6 = t & 63, r15 = l6 & 15, q = l6 >> 4;
  int colo = w * 16 + r15;
  int half = l6 >> 5, li = l6 & 31, ch0 = li * 4;
  const uint4* geg = ge + (size_t)g * EPAD;  // L1/L2-resident edge metadata

  // ---- stage ----
  {
    if (t < NPG) sz[t] = z[a0 + t];
    if (t <= NPG) sstart[t] = gstart[g * (NPG + 1) + t];
    if (t < 48) shead[t] = 0.f;
    ((unsigned*)sb0)[40 * 64 + t] = 0u;  // zero pad rows 40..47
    ((unsigned*)sb1)[40 * 64 + t] = 0u;
    const uint4* tg4 = (const uint4*)ptabg;
    uint4* st4 = (uint4*)ptab;
    for (int i = t; i < PROWS * 32; i += 512) st4[i] = tg4[i];
  }
  __syncthreads();

  // ---- h init from embedding: fragment registers + sb0 bf16 ----
  float hreg[12];
#pragma unroll
  for (int mt = 0; mt < 3; ++mt) {
#pragma unroll
    for (int r = 0; r < 4; ++r) {
      int row = mt * 16 + q * 4 + r;
      float v = 0.f;
      if (row < NPG) {
        v = emb[(size_t)sz[row] * HID + colo];
        sb0[bidx(row, colo)] = bf16rne(v);
      }
      hreg[mt * 4 + r] = v;
    }
  }
  __syncthreads();

  for (int l = 0; l < 3; ++l) {
    const ushort_t* w1t = wtb + (size_t)(l * 3 + 0) * 128 * 128;
    const ushort_t* w2t = wtb + (size_t)(l * 3 + 1) * 128 * 128;
    const ushort_t* lwt = wtb + (size_t)(l * 3 + 2) * 128 * 128;
    if (l > 0) {  // restage pre-packed pair table (pure copy)
      const uint4* tg4 = (const uint4*)(ptabg + (size_t)l * PROWS * 128);
      uint4* st4 = (uint4*)ptab;
      for (int i = t; i < PROWS * 32; i += 512) st4[i] = tg4[i];
    }
    // ---- GEMV1: x1 = h @ w1  (sb0 -> sb1) ----
    {
      short8v bfr[4];
      const ushort_t* wp = w1t + (size_t)colo * 128 + q * 8;
#pragma unroll
      for (int ks = 0; ks < 4; ++ks) bfr[ks] = *(const short8v*)(wp + ks * 32);
#pragma unroll
      for (int mt = 0; mt < 3; ++mt) {
        f32x4 acc = (f32x4){0.f, 0.f, 0.f, 0.f};
#pragma unroll
        for (int ks = 0; ks < 4; ++ks) {
          short8v af = *(const short8v*)&sb0[bidx(mt * 16 + r15, ks * 32 + q * 8)];
          acc = __builtin_amdgcn_mfma_f32_16x16x32_bf16(af, bfr[ks], acc, 0, 0, 0);
        }
#pragma unroll
        for (int r = 0; r < 4; ++r) sb1[bidx(mt * 16 + q * 4 + r, colo)] = bf16rne(acc[r]);
      }
    }
    __syncthreads();
    // ---- edge agg: half-wave pairing; meta from global (VMEM), table+x1 from LDS ----
    {
      const unsigned* b1u = (const unsigned*)sb1;
      unsigned* b0u = (unsigned*)sb0;
      for (int a = w; a < NPG; a += 8) {
        int kb = sstart[a], ke = sstart[a + 1];
        float a0c = 0.f, a1c = 0.f, a2c = 0.f, a3c = 0.f;
        for (int k = kb + half; k < ke; k += 2) {
          uint4 ev = geg[k];
          const unsigned* tb = ptab + ev.z + ch0;
          uint4 pa = *(const uint4*)tb;
          uint4 pb = *(const uint4*)(tb + 256);
          uint2 xv = *(const uint2*)&b1u[(ev.w & 0xffffu) + ((li * 2) ^ (ev.w >> 16))];
          float f0 = fdot2b(ev.x, pa.x, 0.f); f0 = fdot2b(ev.y, pb.x, f0);
          float f1 = fdot2b(ev.x, pa.y, 0.f); f1 = fdot2b(ev.y, pb.y, f1);
          float f2 = fdot2b(ev.x, pa.z, 0.f); f2 = fdot2b(ev.y, pb.z, f2);
          float f3 = fdot2b(ev.x, pa.w, 0.f); f3 = fdot2b(ev.y, pb.w, f3);
          a0c = fmaf(bflo(xv.x), f0, a0c);
          a1c = fmaf(bfhi(xv.x), f1, a1c);
          a2c = fmaf(bflo(xv.y), f2, a2c);
          a3c = fmaf(bfhi(xv.y), f3, a3c);
        }
        a0c += __shfl_xor(a0c, 32);
        a1c += __shfl_xor(a1c, 32);
        a2c += __shfl_xor(a2c, 32);
        a3c += __shfl_xor(a3c, 32);
        if (half == 0) {
          uint2 o;
          o.x = pk2(a0c, a1c);
          o.y = pk2(a2c, a3c);
          *(uint2*)&b0u[(a << 6) + ((li * 2) ^ ((a & 7) << 2))] = o;
        }
      }
    }
    __syncthreads();
    // ---- GEMV2: u = ssp(agg @ w2 + b2)  (sb0 -> sb1) ----
    {
      float bc = cf_b2[(size_t)l * HID + colo];
      short8v bfr[4];
      const ushort_t* wp = w2t + (size_t)colo * 128 + q * 8;
#pragma unroll
      for (int ks = 0; ks < 4; ++ks) bfr[ks] = *(const short8v*)(wp + ks * 32);
#pragma unroll
      for (int mt = 0; mt < 3; ++mt) {
        f32x4 acc = (f32x4){0.f, 0.f, 0.f, 0.f};
#pragma unroll
        for (int ks = 0; ks < 4; ++ks) {
          short8v af = *(const short8v*)&sb0[bidx(mt * 16 + r15, ks * 32 + q * 8)];
          acc = __builtin_amdgcn_mfma_f32_16x16x32_bf16(af, bfr[ks], acc, 0, 0, 0);
        }
#pragma unroll
        for (int r = 0; r < 4; ++r) {
          int row = mt * 16 + q * 4 + r;
          float v = (row < NPG) ? ssp_f(acc[r] + bc) : 0.f;
          sb1[bidx(row, colo)] = bf16rne(v);
        }
      }
    }
    __syncthreads();
    // ---- GEMV3: h += u @ lw + lb  (sb1 -> hreg + sb0 bf16) ----
    {
      float bc = lin_b[(size_t)l * HID + colo];
      short8v bfr[4];
      const ushort_t* wp = lwt + (size_t)colo * 128 + q * 8;
#pragma unroll
      for (int ks = 0; ks < 4; ++ks) bfr[ks] = *(const short8v*)(wp + ks * 32);
#pragma unroll
      for (int mt = 0; mt < 3; ++mt) {
        f32x4 acc = (f32x4){0.f, 0.f, 0.f, 0.f};
#pragma unroll
        for (int ks = 0; ks < 4; ++ks) {
          short8v af = *(const short8v*)&sb1[bidx(mt * 16 + r15, ks * 32 + q * 8)];
          acc = __builtin_amdgcn_mfma_f32_16x16x32_bf16(af, bfr[ks], acc, 0, 0, 0);
        }
#pragma unroll
        for (int r = 0; r < 4; ++r) {
          int row = mt * 16 + q * 4 + r;
          if (row < NPG) {
            float nh = hreg[mt * 4 + r] + acc[r] + bc;
            hreg[mt * 4 + r] = nh;
            sb0[bidx(row, colo)] = bf16rne(nh);
          }
        }
      }
    }
    __syncthreads();
  }

  // ---- head via MFMA: y = ssp(H@hw1+hb1)@hw2; out[g] = sum + 40*hb2 ----
  {
    const ushort_t* h1t = wtb + (size_t)9 * 128 * 128;
    for (int tile = w; tile < 12; tile += 8) {
      int mt = tile >> 2, nt = tile & 3;
      int col = nt * 16 + r15;
      short8v bfr[4];
      const ushort_t* wp = h1t + (size_t)col * 128 + q * 8;
#pragma unroll
      for (int ks = 0; ks < 4; ++ks) bfr[ks] = *(const short8v*)(wp + ks * 32);
      f32x4 acc = (f32x4){0.f, 0.f, 0.f, 0.f};
#pragma unroll
      for (int ks = 0; ks < 4; ++ks) {
        short8v af = *(const short8v*)&sb0[bidx(mt * 16 + r15, ks * 32 + q * 8)];
        acc = __builtin_amdgcn_mfma_f32_16x16x32_bf16(af, bfr[ks], acc, 0, 0, 0);
      }
      float hb = hb1[col];
      float w2v = hw2[col];
#pragma unroll
      for (int r = 0; r < 4; ++r) {
        int row = mt * 16 + q * 4 + r;
        float y = ssp_f(acc[r] + hb) * w2v;
        y += __shfl_xor(y, 1);
        y += __shfl_xor(y, 2);
        y += __shfl_xor(y, 4);
        y += __shfl_xor(y, 8);
        if (r15 == 0 && row < NPG) atomicAdd(&shead[row], y);
      }
    }
  }
  __syncthreads();
  if (w == 0) {
    float v = (l6 < NPG) ? shead[l6] : 0.f;
#pragma unroll
    for (int off = 32; off; off >>= 1) v += __shfl_xor(v, off);
    if (l6 == 0) out[g] = v + (float)NPG * hb2[0];
  }
}

extern "C" void kernel_launch(void* const* d_in, const int* in_sizes, int n_in,
                              void* d_out, int out_size, void* d_ws, size_t ws_size,
                              hipStream_t stream) {
  const float* pos    = (const float*)d_in[0];
  const float* emb    = (const float*)d_in[1];
  const float* mlp_w1 = (const float*)d_in[2];
  const float* mlp_b1 = (const float*)d_in[3];
  const float* mlp_w2 = (const float*)d_in[4];
  const float* mlp_b2 = (const float*)d_in[5];
  const float* cf_w1  = (const float*)d_in[6];
  const float* cf_w2  = (const float*)d_in[7];
  const float* cf_b2  = (const float*)d_in[8];
  const float* lin_w  = (const float*)d_in[9];
  const float* lin_b  = (const float*)d_in[10];
  const float* hw1    = (const float*)d_in[11];
  const float* hb1    = (const float*)d_in[12];
  const float* hw2    = (const float*)d_in[13];
  const float* hb2    = (const float*)d_in[14];
  const int*   z      = (const int*)d_in[15];
  const int*   ei     = (const int*)d_in[17];

  char* wsb = (char*)d_ws;
  uint4*    ge     = (uint4*)wsb;                       // 500*680*16 = 5,440,000
  int*      gstart = (int*)(wsb + 5440000);             // 500*41*4   =    82,000
  unsigned* ptabg  = (unsigned*)(wsb + 5522000);        // 3*81*128*4 =   124,416
  ushort_t* wtb    = (ushort_t*)(wsb + 5646416);        // 10*16384*2 =   327,680
  size_t need = 5646416 + 327680;
  if (ws_size < need) return;

  k_pre<<<571, 512, 0, stream>>>(mlp_w1, mlp_b1, mlp_w2, mlp_b2, cf_w1, cf_w2, lin_w,
                                 hw1, pos, ei, ptabg, wtb, ge, gstart);
  k_mol<<<G_GRAPHS, 512, 0, stream>>>(emb, z, ge, gstart, ptabg, wtb,
                                      cf_b2, lin_b, hb1, hw2, hb2, (float*)d_out);
}

// Round 15
// 102.823 us; speedup vs baseline: 1.1172x; 1.1172x over previous
//
#include <hip/hip_runtime.h>
#include <math.h>

#define N_ATOMS 20000
#define G_GRAPHS 500
#define NPG 40
#define DEG 16
#define E_EDGES (N_ATOMS * DEG)
#define EPM (NPG * DEG)          // 640 real edges per molecule
#define EPAD 680                 // padded capacity (each atom even count)
#define HID 128
#define NF 128
#define TBL2 80
#define TROWS (TBL2 + 2)         // 82 stored rows (grid -1 .. 80)
#define PROWS 81                 // pair rows s=0..80: (row s, row s+1)
#define CUTOFF 10.0f
#define LOG2F_ 0.6931471805599453f

typedef __attribute__((ext_vector_type(8))) short short8v;
typedef __attribute__((ext_vector_type(4))) float f32x4;
typedef __attribute__((ext_vector_type(2))) __bf16 bf16x2;
typedef unsigned short ushort_t;

__device__ __forceinline__ float ssp_f(float x) {
  float ax = fabsf(x);
  return fmaxf(x, 0.0f) + log1pf(expf(-ax)) - LOG2F_;
}
// native RNE float->bf16 (v_cvt_pk_bf16_f32 when paired; RNE == manual round-nearest-even)
__device__ __forceinline__ ushort_t bf16rne(float x) {
  __bf16 b = (__bf16)x;
  return __builtin_bit_cast(ushort_t, b);
}
__device__ __forceinline__ unsigned pk2(float a, float b) {
  return (unsigned)bf16rne(a) | ((unsigned)bf16rne(b) << 16);
}
__device__ __forceinline__ float bflo(unsigned u) { return __uint_as_float(u << 16); }
__device__ __forceinline__ float bfhi(unsigned u) { return __uint_as_float(u & 0xFFFF0000u); }
__device__ __forceinline__ int bidx(int row, int col) {
  return row * 128 + (col ^ ((row & 7) << 3));
}
__device__ __forceinline__ float fdot2b(unsigned a, unsigned b, float c) {
#if defined(__has_builtin) && __has_builtin(__builtin_amdgcn_fdot2_f32_bf16)
  return __builtin_amdgcn_fdot2_f32_bf16(__builtin_bit_cast(bf16x2, a),
                                         __builtin_bit_cast(bf16x2, b), c, false);
#else
  return fmaf(bflo(a), bflo(b), fmaf(bfhi(a), bfhi(b), c));
#endif
}

// ================= merged preamble: table(33) | prep(38) | csr(500) =================
__global__ void __launch_bounds__(512) k_pre(
    const float* __restrict__ mlp_w1, const float* __restrict__ mlp_b1,
    const float* __restrict__ mlp_w2, const float* __restrict__ mlp_b2,
    const float* __restrict__ cf_w1, const float* __restrict__ cf_w2,
    const float* __restrict__ lin_w, const float* __restrict__ hw1,
    const float* __restrict__ pos, const int* __restrict__ ei,
    unsigned* __restrict__ ptabg, ushort_t* __restrict__ wtb,
    uint4* __restrict__ ge, int* __restrict__ gstart) {
  int b = blockIdx.x;
  int t = threadIdx.x;

  if (b < 33) {
    // ---------- filter-table role: 8 rows per block, pair-packed global output ----------
    __shared__ float eaT[NF][8];
    __shared__ float hvT[NF][8];
    int l = b / 11;
    int rbase = (b % 11) * 8;
    const float* w1 = mlp_w1 + (size_t)l * NF * NF;
    const float* b1 = mlp_b1 + (size_t)l * NF;
    const float* w2 = mlp_w2 + (size_t)l * NF * NF;
    const float* b2 = mlp_b2 + (size_t)l * NF;
    ushort_t* pp = (ushort_t*)(ptabg + (size_t)l * PROWS * 128);
    const float hh = CUTOFF / (float)(TBL2 - 1);
    const float delta = CUTOFF / (float)(NF - 1);
    const float coeff = -0.5f / (delta * delta);
    int j = t & 127;
    bool act = t < 128;
    if (act) {
#pragma unroll
      for (int rr = 0; rr < 8; ++rr) {
        float d = ((float)(rbase + rr) - 1.0f) * hh;
        float tt = d - delta * (float)j;
        eaT[j][rr] = expf(coeff * tt * tt);
      }
    }
    __syncthreads();
    float acc[8], wreg[16];
    if (act) {
      float b1j = b1[j];
#pragma unroll
      for (int rr = 0; rr < 8; ++rr) acc[rr] = b1j;
      for (int kb = 0; kb < NF; kb += 16) {
#pragma unroll
        for (int i = 0; i < 16; ++i) wreg[i] = w1[(kb + i) * NF + j];
#pragma unroll
        for (int i = 0; i < 16; ++i) {
          float4 e0 = *(const float4*)&eaT[kb + i][0];
          float4 e1 = *(const float4*)&eaT[kb + i][4];
          float wv = wreg[i];
          acc[0] = fmaf(e0.x, wv, acc[0]); acc[1] = fmaf(e0.y, wv, acc[1]);
          acc[2] = fmaf(e0.z, wv, acc[2]); acc[3] = fmaf(e0.w, wv, acc[3]);
          acc[4] = fmaf(e1.x, wv, acc[4]); acc[5] = fmaf(e1.y, wv, acc[5]);
          acc[6] = fmaf(e1.z, wv, acc[6]); acc[7] = fmaf(e1.w, wv, acc[7]);
        }
      }
#pragma unroll
      for (int rr = 0; rr < 8; ++rr) hvT[j][rr] = ssp_f(acc[rr]);
    }
    __syncthreads();
    if (act) {
      float b2j = b2[j];
#pragma unroll
      for (int rr = 0; rr < 8; ++rr) acc[rr] = b2j;
      for (int kb = 0; kb < NF; kb += 16) {
#pragma unroll
        for (int i = 0; i < 16; ++i) wreg[i] = w2[(kb + i) * NF + j];
#pragma unroll
        for (int i = 0; i < 16; ++i) {
          float4 e0 = *(const float4*)&hvT[kb + i][0];
          float4 e1 = *(const float4*)&hvT[kb + i][4];
          float wv = wreg[i];
          acc[0] = fmaf(e0.x, wv, acc[0]); acc[1] = fmaf(e0.y, wv, acc[1]);
          acc[2] = fmaf(e0.z, wv, acc[2]); acc[3] = fmaf(e0.w, wv, acc[3]);
          acc[4] = fmaf(e1.x, wv, acc[4]); acc[5] = fmaf(e1.y, wv, acc[5]);
          acc[6] = fmaf(e1.z, wv, acc[6]); acc[7] = fmaf(e1.w, wv, acc[7]);
        }
      }
#pragma unroll
      for (int rr = 0; rr < 8; ++rr) {
        int s = rbase + rr;
        if (s < TROWS) {
          float d = ((float)s - 1.0f) * hh;
          float C = 0.5f * (cosf(d * (float)M_PI / CUTOFF) + 1.0f);
          ushort_t v = bf16rne(acc[rr] * C);
          if (s < PROWS) pp[(s * 128 + j) * 2] = v;          // low half of pair s
          if (s >= 1) pp[((s - 1) * 128 + j) * 2 + 1] = v;   // high half of pair s-1
        }
      }
    }
  } else if (b < 71) {
    // ---------- weight transpose role ----------
    __shared__ float tile[32][33];
    int pb = b - 33;
    int tr = (t & 255) >> 5, tc = t & 31;
    bool act = t < 256;
    if (pb < 36) {
      int m = pb >> 2, tj = pb & 3;
      int l = m / 3, ty = m % 3;
      const float* src = (ty == 0 ? cf_w1 : ty == 1 ? cf_w2 : lin_w) + (size_t)l * 128 * 128;
      ushort_t* dst = wtb + (size_t)m * 128 * 128;
      for (int ti = 0; ti < 4; ++ti) {
        __syncthreads();
        if (act) {
#pragma unroll
          for (int i = 0; i < 4; ++i) {
            int r = tr + i * 8;
            tile[r][tc] = src[(ti * 32 + r) * 128 + tj * 32 + tc];
          }
        }
        __syncthreads();
        if (act) {
#pragma unroll
          for (int i = 0; i < 4; ++i) {
            int r = tr + i * 8;
            dst[(tj * 32 + r) * 128 + ti * 32 + tc] = bf16rne(tile[tc][r]);
          }
        }
      }
    } else {
      int tj = pb - 36;
      ushort_t* dst = wtb + (size_t)9 * 128 * 128;
      for (int ti = 0; ti < 4; ++ti) {
        __syncthreads();
        if (act) {
#pragma unroll
          for (int i = 0; i < 4; ++i) {
            int r = tr + i * 8;
            tile[r][tc] = hw1[(ti * 32 + r) * 64 + tj * 32 + tc];
          }
        }
        __syncthreads();
        if (act) {
#pragma unroll
          for (int i = 0; i < 4; ++i) {
            int r = tr + i * 8;
            dst[(tj * 32 + r) * 128 + ti * 32 + tc] = bf16rne(tile[tc][r]);
          }
        }
      }
    }
  } else {
    // ---------- CSR role: distances + cubic weights + even-padded CSR ----------
    __shared__ float spos[NPG * 3];
    __shared__ int cnt[NPG];
    __shared__ int pfx[NPG + 1];
    __shared__ uint4 epk[EPM];
    __shared__ unsigned char ecol[EPM];
    __shared__ short ssidx[EPAD];
    int g = b - 71, a0 = g * NPG;
    if (t < NPG * 3) spos[t] = pos[a0 * 3 + t];
    if (t < NPG) cnt[t] = 0;
    for (int i = t; i < EPAD; i += 512) ssidx[i] = -1;
    __syncthreads();
    int ebase = a0 * DEG;
    const float tscale = (float)(TBL2 - 1) / CUTOFF;
    for (int i = t; i < EPM; i += 512) {
      int r = ei[ebase + i] - a0;
      int c = ei[E_EDGES + ebase + i] - a0;
      float dx = spos[3 * r + 0] - spos[3 * c + 0];
      float dy = spos[3 * r + 1] - spos[3 * c + 1];
      float dz = spos[3 * r + 2] - spos[3 * c + 2];
      float ft = sqrtf(dx * dx + dy * dy + dz * dz) * tscale;
      int i0 = min((int)ft, TBL2 - 2);
      float tt = ft - (float)i0;
      float t2 = tt * tt, t3 = t2 * tt;
      float w0 = 0.5f * (-t3 + 2.f * t2 - tt);
      float w1 = 0.5f * (3.f * t3 - 5.f * t2 + 2.f);
      float w2 = 0.5f * (-3.f * t3 + 4.f * t2 + tt);
      float w3 = 0.5f * (t3 - t2);
      epk[i] = make_uint4(pk2(w0, w1), pk2(w2, w3), (unsigned)(i0 << 7),
                          (unsigned)((r << 6) | (((r & 7) << 2) << 16)));
      ecol[i] = (unsigned char)c;
      atomicAdd(&cnt[c], 1);
    }
    __syncthreads();
    if (t == 0) {
      int s = 0;
      for (int a = 0; a < NPG; ++a) { pfx[a] = s; s += (cnt[a] + 1) & ~1; }
      pfx[NPG] = s;
    }
    __syncthreads();
    int w = t >> 6, lane = t & 63;
    for (int a = w * 5; a < w * 5 + 5; ++a) {
      int p = pfx[a];
#pragma unroll
      for (int ch = 0; ch < EPM / 64; ++ch) {
        int e = ch * 64 + lane;
        bool match = ((int)ecol[e] == a);
        unsigned long long bal = __ballot(match);
        if (match) ssidx[p + __popcll(bal & ((1ull << lane) - 1ull))] = (short)e;
        p += __popcll(bal);
      }
    }
    __syncthreads();
    int ptot = pfx[NPG];
    const uint4 z4 = make_uint4(0u, 0u, 0u, 0u);
    for (int i = t; i < ptot; i += 512) {
      int e = ssidx[i];
      ge[(size_t)g * EPAD + i] = (e >= 0) ? epk[e] : z4;
    }
    if (t <= NPG) gstart[g * (NPG + 1) + t] = pfx[t];
  }
}

// ================= whole model per molecule =================
__global__ void __launch_bounds__(512) k_mol(
    const float* __restrict__ emb, const int* __restrict__ z,
    const uint4* __restrict__ ge, const int* __restrict__ gstart,
    const unsigned* __restrict__ ptabg, const ushort_t* __restrict__ wtb,
    const float* __restrict__ cf_b2, const float* __restrict__ lin_b,
    const float* __restrict__ hb1, const float* __restrict__ hw2,
    const float* __restrict__ hb2, float* __restrict__ out) {
  __shared__ unsigned ptab[PROWS * 128];  // 41,472 B pair-packed table
  __shared__ ushort_t sb0[48 * 128];      // 12,288 B
  __shared__ ushort_t sb1[48 * 128];      // 12,288 B
  __shared__ uint4 sedge[EPAD];           // 10,880 B
  __shared__ int sstart[NPG + 1];
  __shared__ float shead[48];
  int g = blockIdx.x, a0 = g * NPG, t = threadIdx.x;
  int w = t >> 6, l6 = t & 63, r15 = l6 & 15, q = l6 >> 4;
  int colo = w * 16 + r15;
  int half = l6 >> 5, li = l6 & 31, ch0 = li * 4;

  // ---- stage (single barrier: sedge/ptab/sstart staged while h-init reads global) ----
  int ptot = gstart[g * (NPG + 1) + NPG];
  {
    if (t <= NPG) sstart[t] = gstart[g * (NPG + 1) + t];
    const uint4* gsrc = ge + (size_t)g * EPAD;
    for (int i = t; i < ptot; i += 512) sedge[i] = gsrc[i];
    if (t < 48) shead[t] = 0.f;
    ((unsigned*)sb0)[40 * 64 + t] = 0u;  // zero pad rows 40..47
    ((unsigned*)sb1)[40 * 64 + t] = 0u;
    const uint4* tg4 = (const uint4*)ptabg;
    uint4* st4 = (uint4*)ptab;
    for (int i = t; i < PROWS * 32; i += 512) st4[i] = tg4[i];
  }
  // ---- h init from embedding (per-thread global z read; no LDS dependency) ----
  float hreg[12];
#pragma unroll
  for (int mt = 0; mt < 3; ++mt) {
#pragma unroll
    for (int r = 0; r < 4; ++r) {
      int row = mt * 16 + q * 4 + r;
      float v = 0.f;
      if (row < NPG) {
        v = emb[(size_t)z[a0 + row] * HID + colo];
        sb0[bidx(row, colo)] = bf16rne(v);
      }
      hreg[mt * 4 + r] = v;
    }
  }
  __syncthreads();

  for (int l = 0; l < 3; ++l) {
    const ushort_t* w1t = wtb + (size_t)(l * 3 + 0) * 128 * 128;
    const ushort_t* w2t = wtb + (size_t)(l * 3 + 1) * 128 * 128;
    const ushort_t* lwt = wtb + (size_t)(l * 3 + 2) * 128 * 128;
    if (l > 0) {  // restage pre-packed pair table (pure copy; ptab unread until post-barrier)
      const uint4* tg4 = (const uint4*)(ptabg + (size_t)l * PROWS * 128);
      uint4* st4 = (uint4*)ptab;
      for (int i = t; i < PROWS * 32; i += 512) st4[i] = tg4[i];
    }
    // ---- GEMV1: x1 = h @ w1  (sb0 -> sb1) ----
    {
      short8v bfr[4];
      const ushort_t* wp = w1t + (size_t)colo * 128 + q * 8;
#pragma unroll
      for (int ks = 0; ks < 4; ++ks) bfr[ks] = *(const short8v*)(wp + ks * 32);
#pragma unroll
      for (int mt = 0; mt < 3; ++mt) {
        f32x4 acc = (f32x4){0.f, 0.f, 0.f, 0.f};
#pragma unroll
        for (int ks = 0; ks < 4; ++ks) {
          short8v af = *(const short8v*)&sb0[bidx(mt * 16 + r15, ks * 32 + q * 8)];
          acc = __builtin_amdgcn_mfma_f32_16x16x32_bf16(af, bfr[ks], acc, 0, 0, 0);
        }
#pragma unroll
        for (int r = 0; r < 4; ++r) sb1[bidx(mt * 16 + q * 4 + r, colo)] = bf16rne(acc[r]);
      }
    }
    __syncthreads();
    // ---- edge agg: half-wave pairing, even-padded, all-LDS (sb1 -> sb0) ----
    {
      const unsigned* b1u = (const unsigned*)sb1;
      unsigned* b0u = (unsigned*)sb0;
      for (int a = w; a < NPG; a += 8) {
        int kb = sstart[a], ke = sstart[a + 1];
        float a0c = 0.f, a1c = 0.f, a2c = 0.f, a3c = 0.f;
        for (int k = kb + half; k < ke; k += 2) {
          uint4 ev = sedge[k];
          const unsigned* tb = ptab + ev.z + ch0;
          uint4 pa = *(const uint4*)tb;
          uint4 pb = *(const uint4*)(tb + 256);
          uint2 xv = *(const uint2*)&b1u[(ev.w & 0xffffu) + ((li * 2) ^ (ev.w >> 16))];
          float f0 = fdot2b(ev.x, pa.x, 0.f); f0 = fdot2b(ev.y, pb.x, f0);
          float f1 = fdot2b(ev.x, pa.y, 0.f); f1 = fdot2b(ev.y, pb.y, f1);
          float f2 = fdot2b(ev.x, pa.z, 0.f); f2 = fdot2b(ev.y, pb.z, f2);
          float f3 = fdot2b(ev.x, pa.w, 0.f); f3 = fdot2b(ev.y, pb.w, f3);
          a0c = fmaf(bflo(xv.x), f0, a0c);
          a1c = fmaf(bfhi(xv.x), f1, a1c);
          a2c = fmaf(bflo(xv.y), f2, a2c);
          a3c = fmaf(bfhi(xv.y), f3, a3c);
        }
        a0c += __shfl_xor(a0c, 32);
        a1c += __shfl_xor(a1c, 32);
        a2c += __shfl_xor(a2c, 32);
        a3c += __shfl_xor(a3c, 32);
        if (half == 0) {
          uint2 o;
          o.x = pk2(a0c, a1c);
          o.y = pk2(a2c, a3c);
          *(uint2*)&b0u[(a << 6) + ((li * 2) ^ ((a & 7) << 2))] = o;
        }
      }
    }
    __syncthreads();
    // ---- GEMV2: u = ssp(agg @ w2 + b2)  (sb0 -> sb1) ----
    {
      float bc = cf_b2[(size_t)l * HID + colo];
      short8v bfr[4];
      const ushort_t* wp = w2t + (size_t)colo * 128 + q * 8;
#pragma unroll
      for (int ks = 0; ks < 4; ++ks) bfr[ks] = *(const short8v*)(wp + ks * 32);
#pragma unroll
      for (int mt = 0; mt < 3; ++mt) {
        f32x4 acc = (f32x4){0.f, 0.f, 0.f, 0.f};
#pragma unroll
        for (int ks = 0; ks < 4; ++ks) {
          short8v af = *(const short8v*)&sb0[bidx(mt * 16 + r15, ks * 32 + q * 8)];
          acc = __builtin_amdgcn_mfma_f32_16x16x32_bf16(af, bfr[ks], acc, 0, 0, 0);
        }
#pragma unroll
        for (int r = 0; r < 4; ++r) {
          int row = mt * 16 + q * 4 + r;
          float v = (row < NPG) ? ssp_f(acc[r] + bc) : 0.f;
          sb1[bidx(row, colo)] = bf16rne(v);
        }
      }
    }
    __syncthreads();
    // ---- GEMV3: h += u @ lw + lb  (sb1 -> hreg + sb0 bf16) ----
    {
      float bc = lin_b[(size_t)l * HID + colo];
      short8v bfr[4];
      const ushort_t* wp = lwt + (size_t)colo * 128 + q * 8;
#pragma unroll
      for (int ks = 0; ks < 4; ++ks) bfr[ks] = *(const short8v*)(wp + ks * 32);
#pragma unroll
      for (int mt = 0; mt < 3; ++mt) {
        f32x4 acc = (f32x4){0.f, 0.f, 0.f, 0.f};
#pragma unroll
        for (int ks = 0; ks < 4; ++ks) {
          short8v af = *(const short8v*)&sb1[bidx(mt * 16 + r15, ks * 32 + q * 8)];
          acc = __builtin_amdgcn_mfma_f32_16x16x32_bf16(af, bfr[ks], acc, 0, 0, 0);
        }
#pragma unroll
        for (int r = 0; r < 4; ++r) {
          int row = mt * 16 + q * 4 + r;
          if (row < NPG) {
            float nh = hreg[mt * 4 + r] + acc[r] + bc;
            hreg[mt * 4 + r] = nh;
            sb0[bidx(row, colo)] = bf16rne(nh);
          }
        }
      }
    }
    __syncthreads();
  }

  // ---- head via MFMA: y = ssp(H@hw1+hb1)@hw2; out[g] = sum + 40*hb2 ----
  {
    const ushort_t* h1t = wtb + (size_t)9 * 128 * 128;
    for (int tile = w; tile < 12; tile += 8) {
      int mt = tile >> 2, nt = tile & 3;
      int col = nt * 16 + r15;
      short8v bfr[4];
      const ushort_t* wp = h1t + (size_t)col * 128 + q * 8;
#pragma unroll
      for (int ks = 0; ks < 4; ++ks) bfr[ks] = *(const short8v*)(wp + ks * 32);
      f32x4 acc = (f32x4){0.f, 0.f, 0.f, 0.f};
#pragma unroll
      for (int ks = 0; ks < 4; ++ks) {
        short8v af = *(const short8v*)&sb0[bidx(mt * 16 + r15, ks * 32 + q * 8)];
        acc = __builtin_amdgcn_mfma_f32_16x16x32_bf16(af, bfr[ks], acc, 0, 0, 0);
      }
      float hb = hb1[col];
      float w2v = hw2[col];
#pragma unroll
      for (int r = 0; r < 4; ++r) {
        int row = mt * 16 + q * 4 + r;
        float y = ssp_f(acc[r] + hb) * w2v;
        y += __shfl_xor(y, 1);
        y += __shfl_xor(y, 2);
        y += __shfl_xor(y, 4);
        y += __shfl_xor(y, 8);
        if (r15 == 0 && row < NPG) atomicAdd(&shead[row], y);
      }
    }
  }
  __syncthreads();
  if (w == 0) {
    float v = (l6 < NPG) ? shead[l6] : 0.f;
#pragma unroll
    for (int off = 32; off; off >>= 1) v += __shfl_xor(v, off);
    if (l6 == 0) out[g] = v + (float)NPG * hb2[0];
  }
}

extern "C" void kernel_launch(void* const* d_in, const int* in_sizes, int n_in,
                              void* d_out, int out_size, void* d_ws, size_t ws_size,
                              hipStream_t stream) {
  const float* pos    = (const float*)d_in[0];
  const float* emb    = (const float*)d_in[1];
  const float* mlp_w1 = (const float*)d_in[2];
  const float* mlp_b1 = (const float*)d_in[3];
  const float* mlp_w2 = (const float*)d_in[4];
  const float* mlp_b2 = (const float*)d_in[5];
  const float* cf_w1  = (const float*)d_in[6];
  const float* cf_w2  = (const float*)d_in[7];
  const float* cf_b2  = (const float*)d_in[8];
  const float* lin_w  = (const float*)d_in[9];
  const float* lin_b  = (const float*)d_in[10];
  const float* hw1    = (const float*)d_in[11];
  const float* hb1    = (const float*)d_in[12];
  const float* hw2    = (const float*)d_in[13];
  const float* hb2    = (const float*)d_in[14];
  const int*   z      = (const int*)d_in[15];
  const int*   ei     = (const int*)d_in[17];

  char* wsb = (char*)d_ws;
  uint4*    ge     = (uint4*)wsb;                       // 500*680*16 = 5,440,000
  int*      gstart = (int*)(wsb + 5440000);             // 500*41*4   =    82,000
  unsigned* ptabg  = (unsigned*)(wsb + 5522000);        // 3*81*128*4 =   124,416
  ushort_t* wtb    = (ushort_t*)(wsb + 5646416);        // 10*16384*2 =   327,680
  size_t need = 5646416 + 327680;
  if (ws_size < need) return;

  k_pre<<<571, 512, 0, stream>>>(mlp_w1, mlp_b1, mlp_w2, mlp_b2, cf_w1, cf_w2, lin_w,
                                 hw1, pos, ei, ptabg, wtb, ge, gstart);
  k_mol<<<G_GRAPHS, 512, 0, stream>>>(emb, z, ge, gstart, ptabg, wtb,
                                      cf_b2, lin_b, hb1, hw2, hb2, (float*)d_out);
}